// Round 8
// baseline (1091.755 us; speedup 1.0000x reference)
//
#include <hip/hip_runtime.h>

#define LOG2E 1.4426950408889634f

typedef _Float16 h2t __attribute__((ext_vector_type(2)));

// broadcast lane `srclane`'s value to all lanes via v_readlane (SGPR result).
__device__ __forceinline__ float rl(float v, int srclane) {
  return __int_as_float(__builtin_amdgcn_readlane(__float_as_int(v), srclane));
}
__device__ __forceinline__ unsigned rlu(unsigned v, int srclane) {
  return (unsigned)__builtin_amdgcn_readlane((int)v, srclane);
}
__device__ __forceinline__ float rfl(float v) {
  return __int_as_float(__builtin_amdgcn_readfirstlane(__float_as_int(v)));
}

// quad broadcast via DPP quad_perm
template<int CTL>
__device__ __forceinline__ float qb(float v) {
  return __int_as_float(__builtin_amdgcn_update_dpp(0, __float_as_int(v), CTL, 0xF, 0xF, true));
}

__device__ __forceinline__ float fast_rcp(float x)  { return __builtin_amdgcn_rcpf(x); }
__device__ __forceinline__ float fast_exp2(float x) { return __builtin_amdgcn_exp2f(x); }

__device__ __forceinline__ float sigf(float x) {
  return fast_rcp(1.0f + fast_exp2(-LOG2E * x));
}
__device__ __forceinline__ float tanhfast(float x) {
  return fmaf(fast_rcp(1.0f + fast_exp2(-2.0f * LOG2E * x)), 2.0f, -1.0f);
}

#if defined(__has_builtin)
#if __has_builtin(__builtin_amdgcn_fdot2)
#define USE_FDOT2 1
#endif
#endif

__device__ __forceinline__ float fd2(unsigned q, h2t w, float acc) {
#if defined(USE_FDOT2)
  return __builtin_amdgcn_fdot2(__builtin_bit_cast(h2t, q), w, acc, false);
#else
  h2t a = __builtin_elementwise_fma(__builtin_bit_cast(h2t, q), w,
                                    (h2t){(_Float16)0, (_Float16)0});
  return acc + (float)a.x + (float)a.y;
#endif
}

// one LSTM recurrence step (lane layout: r = g*16+j, g=lane&3).
// q[0..7]: f16 h-pairs broadcast at the END of the previous step (loop-rotated
// so the readlane->SGPR hazard is buried under stores/prefetch, not heading
// the critical chain). fdot2 tree: 4 chains of depth 2 + 2-level add tree.
__device__ __forceinline__ void lstm_step(float pre, const h2t* __restrict__ w2,
                                          float amul, float aadd,
                                          unsigned* __restrict__ q,
                                          float& ct, float& h) {
  float c0 = fd2(q[0], w2[0], pre);
  float c1 = fd2(q[1], w2[1], 0.f);
  float c2 = fd2(q[4], w2[4], 0.f);
  float c3 = fd2(q[5], w2[5], 0.f);
  c0 = fd2(q[2], w2[2], c0);
  c1 = fd2(q[3], w2[3], c1);
  c2 = fd2(q[6], w2[6], c2);
  c3 = fd2(q[7], w2[7], c3);
  const float m = (c0 + c1) + (c2 + c3);          // = -ksc * preact
  const float e   = fast_exp2(m);
  const float sgm = fast_rcp(1.0f + e);           // sigmoid(ksc'*P)
  const float act = fmaf(sgm, amul, aadd);        // sigmoid / -2log2e*tanh
  const float fa = qb<0x55>(act);
  const float ga = qb<0xAA>(act);                 // = -2log2e * g
  const float oa = qb<0xFF>(act);
  ct = fmaf(fa, ct, act * ga);                    // act == ia on g=0 lanes
  const float e2 = fast_exp2(ct);
  const float tc = fmaf(fast_rcp(1.0f + e2), 2.0f, -1.0f);   // tanh(c)
  h = oa * tc;
  // pack f16 pair (h_self, h_lane+4): row_shl:4 + pkrtz, then broadcast the
  // 8 pairs for the NEXT step right here (rotation).
  const int hpart = __builtin_amdgcn_update_dpp(
      0, __float_as_int(h), 0x104, 0xF, 0xF, true);
  const unsigned hpk = __builtin_bit_cast(unsigned,
      __builtin_amdgcn_cvt_pkrtz(h, __int_as_float(hpart)));
  q[0] = rlu(hpk,  0);
  q[1] = rlu(hpk,  8);
  q[2] = rlu(hpk, 16);
  q[3] = rlu(hpk, 24);
  q[4] = rlu(hpk, 32);
  q[5] = rlu(hpk, 40);
  q[6] = rlu(hpk, 48);
  q[7] = rlu(hpk, 56);
}

// One bidirectional-LSTM layer. grid = 256 blocks (b*2+dir), block = 192 (3 waves).
// One chain per consumer wave (only per-step latency matters: 256 chains/256 CUs).
// Ring layout [group][swizzled-lane][4]: lane dword offset = 4*lane + 4*(lane>>3)
// keeps 16B alignment AND spreads each 8-lane phase across 32 distinct banks
// (R7's plain [lane][4] had lanes {l,l+8,..} on one bank -> 1.8M conflict cycles).
// Wave 0: consumer. Waves 1,2: phase A produce xW; phase B drain h (chunk c-2).
template<int IN, bool LAST>
__global__ __launch_bounds__(192, 1) void bilstm_layer(
    const float* __restrict__ x,     // (B,T,IN)
    const float* __restrict__ Wih,   // (2,64,IN)
    const float* __restrict__ Whh,   // (2,64,16)
    const float* __restrict__ bias,  // (2,64)
    float* __restrict__ out)         // (B,T,32) or (B,256,32) if LAST
{
  constexpr int T = 2048;
  constexpr int C = 64;          // ring chunk (steps)
  constexpr int NG = C / 4;      // groups per chunk (16)
  constexpr int GS = 288;        // group stride in dwords (max swizzled offset 280+4)
  constexpr int NCH = T / C;
  constexpr int NSLOT = NCH + 2; // xW produce -> consume -> h drain
  constexpr int NV4 = IN / 4;
  const int b    = blockIdx.x >> 1;
  const int dir  = blockIdx.x & 1;
  const int tid  = threadIdx.x;
  const int wave = tid >> 6;
  const int lane = tid & 63;
  const int g = lane & 3;
  const int r = g * 16 + (lane >> 2);
  const int dl = lane * 4 + ((lane >> 3) << 2);   // swizzled dword offset
  const float ksc = (g == 2) ? 2.0f * LOG2E : LOG2E;

  __shared__ float ring [2][(NG + 1) * GS];  // xW staging (+1 group: prefetch pad)
  __shared__ float ring2[2][NG * GS];        // h staging (consumer -> drainers)

  if (wave >= 1) {
    // ---------------- producers ----------------
    const int pw = wave - 1;
    float wih[IN];
    const float* wr = Wih + (size_t)(dir * 64 + r) * IN;
#pragma unroll
    for (int k = 0; k < IN; ++k) wih[k] = -ksc * wr[k];
    const float bneg = -ksc * bias[dir * 64 + r];
    const float* xb = x + (size_t)b * T * IN;
    const int sl = lane >> 4;    // h-drain: step sub-index 0..3
    const int jj = lane & 15;    // h-drain: hidden index
    const int dj = 16 * jj + ((jj >> 1) << 2);    // = swizzle of lane 4*jj
    for (int c = 0; c < NSLOT; ++c) {
      // phase A: produce xW(chunk c), groups [pw*8, pw*8+8)
      if (c < NCH) {
        const int tt0  = c * C;
        const int tmin = dir ? (T - C - tt0) : tt0;
        const float* src = xb + (size_t)(tmin + lane) * IN;
        float4 xr[NV4];
#pragma unroll
        for (int v = 0; v < NV4; ++v) xr[v] = *(const float4*)(src + 4 * v);
        float* buf = ring[c & 1] + dl;
        for (int mg = pw * 8; mg < pw * 8 + 8; ++mg) {
          float4 acc4;
          float* ap = &acc4.x;
#pragma unroll
          for (int u = 0; u < 4; ++u) {
            const int s   = mg * 4 + u;
            const int row = dir ? (C - 1 - s) : s;
            float a0 = bneg, a1 = 0.0f;
#pragma unroll
            for (int v = 0; v < NV4; ++v) {
              a0 = fmaf(rl(xr[v].x, row), wih[4 * v + 0], a0);
              a1 = fmaf(rl(xr[v].y, row), wih[4 * v + 1], a1);
              a0 = fmaf(rl(xr[v].z, row), wih[4 * v + 2], a0);
              a1 = fmaf(rl(xr[v].w, row), wih[4 * v + 3], a1);
            }
            ap[u] = a0 + a1;   // = -ksc*(Wih·x_t + b)
          }
          *(float4*)(buf + mg * GS) = acc4;        // ds_write_b128, de-conflicted
        }
      }
      // phase B: drain h(chunk c-2) to global
      if (c >= 2 && c - 2 < NCH) {
        const int d = c - 2;
        const float* r2 = ring2[d & 1];
        for (int s0 = pw * 32; s0 < pw * 32 + 32; s0 += 4) {
          const int s  = s0 + sl;
          const float hv = r2[(s >> 2) * GS + dj + (s & 3)];
          const int tt = d * C + s;
          const int t  = dir ? (T - 1 - tt) : tt;
          if (!LAST) {
            out[((size_t)b * T + t) * 32 + dir * 16 + jj] = hv;
          } else if ((t & 7) == 7) {
            out[((size_t)b * 256 + (t >> 3)) * 32 + dir * 16 + jj] = hv;
          }
        }
      }
      __syncthreads();
    }
  } else {
    // ---------------- consumer (recurrence) ----------------
    h2t w2[8];
    {
      const float* wr = Whh + (size_t)(dir * 64 + r) * 16;
#pragma unroll
      for (int p = 0; p < 8; ++p) {
        h2t w;
        w.x = (_Float16)(-ksc * wr[2 * p]);
        w.y = (_Float16)(-ksc * wr[2 * p + 1]);
        w2[p] = w;
      }
    }
    const float amul = (g == 2) ? -4.0f * LOG2E : 1.0f;
    const float aadd = (g == 2) ?  2.0f * LOG2E : 0.0f;
    float ct = 0.0f, h = 0.0f;
    unsigned q[8] = {0, 0, 0, 0, 0, 0, 0, 0};   // h==0 initially
    for (int c = 0; c < NSLOT; ++c) {
      if (c >= 1 && c <= NCH) {
        const float* bp = ring [(c - 1) & 1] + dl;
        float*       hb = ring2[(c - 1) & 1] + dl;
        float4 cur = *(const float4*)(bp);          // group 0
        for (int mg = 0; mg < NG; ++mg) {
          const float4 nxt = *(const float4*)(bp + (mg + 1) * GS);  // pad: safe
          float4 hv4;
          lstm_step(cur.x, w2, amul, aadd, q, ct, h); hv4.x = h;
          lstm_step(cur.y, w2, amul, aadd, q, ct, h); hv4.y = h;
          lstm_step(cur.z, w2, amul, aadd, q, ct, h); hv4.z = h;
          lstm_step(cur.w, w2, amul, aadd, q, ct, h); hv4.w = h;
          *(float4*)(hb + mg * GS) = hv4;           // ds_write_b128
          cur = nxt;
        }
      }
      __syncthreads();
    }
  }
}

// Precompute layer-0 xW for the unidirectional stack: xw0[b][t][g] = ub0[g] + uWih0[g]·x
__global__ __launch_bounds__(256) void uni_xw0(
    const float* __restrict__ dsb,    // (B,256,32)
    const float* __restrict__ uWih0,  // (4,32)
    const float* __restrict__ ub,     // (4,4) — row 0 used
    float* __restrict__ xw0)          // (B,256,4)
{
  const int b = blockIdx.x;
  const int t = threadIdx.x;
  const float* xp = dsb + ((size_t)b * 256 + t) * 32;
  float xv[32];
#pragma unroll
  for (int k = 0; k < 32; k += 4) {
    const float4 v = *(const float4*)(xp + k);
    xv[k] = v.x; xv[k + 1] = v.y; xv[k + 2] = v.z; xv[k + 3] = v.w;
  }
  float4 o;
  float* po = &o.x;
#pragma unroll
  for (int gg = 0; gg < 4; ++gg) {
    float a0 = ub[gg], a1 = 0.f;
#pragma unroll
    for (int k = 0; k < 32; k += 2) {
      a0 = fmaf(uWih0[gg * 32 + k],     xv[k],     a0);
      a1 = fmaf(uWih0[gg * 32 + k + 1], xv[k + 1], a1);
    }
    po[gg] = a0 + a1;
  }
  *(float4*)(xw0 + ((size_t)b * 256 + t) * 4) = o;
}

// Fused 4-layer unidirectional stack (HU=1), software-pipelined: iteration i
// steps l0@t=i, l1@t=i-1, l2@t=i-2, l3@t=i-3 — 4 independent cells per
// iteration = 4-way ILP in one wave. lane = batch element.
__global__ __launch_bounds__(64, 1) void uni_stack(
    const float* __restrict__ xw0,   // (B,256,4) pre-biased layer-0 xW
    const float* __restrict__ uWih,  // (3,4,1)
    const float* __restrict__ uWhh,  // (4,4,1)
    const float* __restrict__ ub,    // (4,4)
    float* __restrict__ out)         // (B,256)
{
  const int b = blockIdx.x * 64 + threadIdx.x;
  float whh[4][4], wih[3][4], bs[3][4];
#pragma unroll
  for (int l = 0; l < 4; ++l)
#pragma unroll
    for (int gg = 0; gg < 4; ++gg) whh[l][gg] = rfl(uWhh[l * 4 + gg]);
#pragma unroll
  for (int l = 0; l < 3; ++l)
#pragma unroll
    for (int gg = 0; gg < 4; ++gg) {
      wih[l][gg] = rfl(uWih[l * 4 + gg]);
      bs[l][gg]  = rfl(ub[(l + 1) * 4 + gg]);
    }
  float h[4] = {0, 0, 0, 0}, c[4] = {0, 0, 0, 0};
  const float4* xp = (const float4*)(xw0 + (size_t)b * 256 * 4);
  float* op = out + (size_t)b * 256;
  for (int i = 0; i < 256 + 3; ++i) {
    const float h0p = h[0], h1p = h[1], h2p = h[2];  // previous-iteration values
    if (i < 256) {
      const float4 xw = xp[i];
      const float i0 = sigf(fmaf(whh[0][0], h[0], xw.x));
      const float f0 = sigf(fmaf(whh[0][1], h[0], xw.y));
      const float g0 = tanhfast(fmaf(whh[0][2], h[0], xw.z));
      const float o0 = sigf(fmaf(whh[0][3], h[0], xw.w));
      c[0] = fmaf(f0, c[0], i0 * g0);
      h[0] = o0 * tanhfast(c[0]);
    }
    if (i >= 1 && i < 257) {
      const float pi  = fmaf(whh[1][0], h[1], fmaf(wih[0][0], h0p, bs[0][0]));
      const float pf  = fmaf(whh[1][1], h[1], fmaf(wih[0][1], h0p, bs[0][1]));
      const float pg  = fmaf(whh[1][2], h[1], fmaf(wih[0][2], h0p, bs[0][2]));
      const float po_ = fmaf(whh[1][3], h[1], fmaf(wih[0][3], h0p, bs[0][3]));
      const float il = sigf(pi), fl = sigf(pf), gl = tanhfast(pg), ol = sigf(po_);
      c[1] = fmaf(fl, c[1], il * gl);
      h[1] = ol * tanhfast(c[1]);
    }
    if (i >= 2 && i < 258) {
      const float pi  = fmaf(whh[2][0], h[2], fmaf(wih[1][0], h1p, bs[1][0]));
      const float pf  = fmaf(whh[2][1], h[2], fmaf(wih[1][1], h1p, bs[1][1]));
      const float pg  = fmaf(whh[2][2], h[2], fmaf(wih[1][2], h1p, bs[1][2]));
      const float po_ = fmaf(whh[2][3], h[2], fmaf(wih[1][3], h1p, bs[1][3]));
      const float il = sigf(pi), fl = sigf(pf), gl = tanhfast(pg), ol = sigf(po_);
      c[2] = fmaf(fl, c[2], il * gl);
      h[2] = ol * tanhfast(c[2]);
    }
    if (i >= 3) {
      const float pi  = fmaf(whh[3][0], h[3], fmaf(wih[2][0], h2p, bs[2][0]));
      const float pf  = fmaf(whh[3][1], h[3], fmaf(wih[2][1], h2p, bs[2][1]));
      const float pg  = fmaf(whh[3][2], h[3], fmaf(wih[2][2], h2p, bs[2][2]));
      const float po_ = fmaf(whh[3][3], h[3], fmaf(wih[2][3], h2p, bs[2][3]));
      const float il = sigf(pi), fl = sigf(pf), gl = tanhfast(pg), ol = sigf(po_);
      c[3] = fmaf(fl, c[3], il * gl);
      h[3] = ol * tanhfast(c[3]);
      op[i - 3] = h[3];
    }
  }
}

extern "C" void kernel_launch(void* const* d_in, const int* in_sizes, int n_in,
                              void* d_out, int out_size, void* d_ws, size_t ws_size,
                              hipStream_t stream)
{
  (void)in_sizes; (void)n_in; (void)out_size; (void)ws_size;
  const float* r_c_s = (const float*)d_in[0];
  const float* bWih0 = (const float*)d_in[1];
  const float* bWih  = (const float*)d_in[2];
  const float* bWhh  = (const float*)d_in[3];
  const float* bb    = (const float*)d_in[4];
  const float* uWih0 = (const float*)d_in[5];
  const float* uWih  = (const float*)d_in[6];
  const float* uWhh  = (const float*)d_in[7];
  const float* ub    = (const float*)d_in[8];
  float* outp = (float*)d_out;

  // workspace layout (floats): two (B,T,32) ping-pong, (B,256,32) downsample, (B,256,4) uni-xW
  float* x0  = (float*)d_ws;
  float* x1  = x0  + (size_t)128 * 2048 * 32;
  float* dsb = x1  + (size_t)128 * 2048 * 32;
  float* xw0 = dsb + (size_t)128 * 256 * 32;

  const dim3 grid(256), block(192);
  bilstm_layer<24, false><<<grid, block, 0, stream>>>(r_c_s, bWih0,               bWhh + 0,               bb + 0,          x0);
  bilstm_layer<32, false><<<grid, block, 0, stream>>>(x0,    bWih + 0 * 2*64*32,  bWhh + 1 * 2*64*16,     bb + 1 * 2*64,   x1);
  bilstm_layer<32, false><<<grid, block, 0, stream>>>(x1,    bWih + 1 * 2*64*32,  bWhh + 2 * 2*64*16,     bb + 2 * 2*64,   x0);
  bilstm_layer<32, true ><<<grid, block, 0, stream>>>(x0,    bWih + 2 * 2*64*32,  bWhh + 3 * 2*64*16,     bb + 3 * 2*64,   dsb);
  uni_xw0 <<<dim3(128), dim3(256), 0, stream>>>(dsb, uWih0, ub, xw0);
  uni_stack<<<dim3(2),   dim3(64),  0, stream>>>(xw0, uWih, uWhh, ub, outp);
}

// Round 9
// 1020.366 us; speedup vs baseline: 1.0700x; 1.0700x over previous
//
#include <hip/hip_runtime.h>

#define LOG2E 1.4426950408889634f

typedef _Float16 h2t __attribute__((ext_vector_type(2)));

// broadcast lane `srclane`'s value to all lanes via v_readlane (SGPR result).
__device__ __forceinline__ float rl(float v, int srclane) {
  return __int_as_float(__builtin_amdgcn_readlane(__float_as_int(v), srclane));
}
__device__ __forceinline__ unsigned rlu(unsigned v, int srclane) {
  return (unsigned)__builtin_amdgcn_readlane((int)v, srclane);
}
__device__ __forceinline__ float rfl(float v) {
  return __int_as_float(__builtin_amdgcn_readfirstlane(__float_as_int(v)));
}

// quad broadcast via DPP quad_perm
template<int CTL>
__device__ __forceinline__ float qb(float v) {
  return __int_as_float(__builtin_amdgcn_update_dpp(0, __float_as_int(v), CTL, 0xF, 0xF, true));
}

__device__ __forceinline__ float fast_rcp(float x)  { return __builtin_amdgcn_rcpf(x); }
__device__ __forceinline__ float fast_exp2(float x) { return __builtin_amdgcn_exp2f(x); }

__device__ __forceinline__ float sigf(float x) {
  return fast_rcp(1.0f + fast_exp2(-LOG2E * x));
}
__device__ __forceinline__ float tanhfast(float x) {
  return fmaf(fast_rcp(1.0f + fast_exp2(-2.0f * LOG2E * x)), 2.0f, -1.0f);
}

#if defined(__has_builtin)
#if __has_builtin(__builtin_amdgcn_fdot2)
#define USE_FDOT2 1
#endif
#endif

// one LSTM recurrence step (lane layout: r = g*16+j, g=lane&3) — R7 version
// verbatim (213.5 µs/layer proven; R8's tree+rotation variant cost +14 cyc/step).
// hpk holds the f16 pair (h_{2p}, h_{2p+1}) valid on lanes 8p (packed last step).
__device__ __forceinline__ void lstm_step(float pre, const h2t* __restrict__ w2,
                                          float amul, float aadd,
                                          unsigned& hpk, float& ct, float& h) {
  const unsigned q0 = rlu(hpk,  0);
  const unsigned q1 = rlu(hpk,  8);
  const unsigned q2 = rlu(hpk, 16);
  const unsigned q3 = rlu(hpk, 24);
  const unsigned q4 = rlu(hpk, 32);
  const unsigned q5 = rlu(hpk, 40);
  const unsigned q6 = rlu(hpk, 48);
  const unsigned q7 = rlu(hpk, 56);
#if defined(USE_FDOT2)
  float a0 = pre, a1 = 0.f;
  a0 = __builtin_amdgcn_fdot2(__builtin_bit_cast(h2t, q0), w2[0], a0, false);
  a1 = __builtin_amdgcn_fdot2(__builtin_bit_cast(h2t, q4), w2[4], a1, false);
  a0 = __builtin_amdgcn_fdot2(__builtin_bit_cast(h2t, q1), w2[1], a0, false);
  a1 = __builtin_amdgcn_fdot2(__builtin_bit_cast(h2t, q5), w2[5], a1, false);
  a0 = __builtin_amdgcn_fdot2(__builtin_bit_cast(h2t, q2), w2[2], a0, false);
  a1 = __builtin_amdgcn_fdot2(__builtin_bit_cast(h2t, q6), w2[6], a1, false);
  a0 = __builtin_amdgcn_fdot2(__builtin_bit_cast(h2t, q3), w2[3], a0, false);
  a1 = __builtin_amdgcn_fdot2(__builtin_bit_cast(h2t, q7), w2[7], a1, false);
  const float m = a0 + a1;                        // = -ksc * preact
#else
  h2t aA = {(_Float16)0, (_Float16)0};
  h2t aB = {(_Float16)0, (_Float16)0};
  aA = __builtin_elementwise_fma(__builtin_bit_cast(h2t, q0), w2[0], aA);
  aB = __builtin_elementwise_fma(__builtin_bit_cast(h2t, q4), w2[4], aB);
  aA = __builtin_elementwise_fma(__builtin_bit_cast(h2t, q1), w2[1], aA);
  aB = __builtin_elementwise_fma(__builtin_bit_cast(h2t, q5), w2[5], aB);
  aA = __builtin_elementwise_fma(__builtin_bit_cast(h2t, q2), w2[2], aA);
  aB = __builtin_elementwise_fma(__builtin_bit_cast(h2t, q6), w2[6], aB);
  aA = __builtin_elementwise_fma(__builtin_bit_cast(h2t, q3), w2[3], aA);
  aB = __builtin_elementwise_fma(__builtin_bit_cast(h2t, q7), w2[7], aB);
  aA = aA + aB;
  const float m = (pre + (float)aA.x) + (float)aA.y;
#endif
  const float e   = fast_exp2(m);
  const float sgm = fast_rcp(1.0f + e);           // sigmoid(ksc'*P)
  const float act = fmaf(sgm, amul, aadd);        // sigmoid / -2log2e*tanh
  const float fa = qb<0x55>(act);
  const float ga = qb<0xAA>(act);                 // = -2log2e * g
  const float oa = qb<0xFF>(act);
  ct = fmaf(fa, ct, act * ga);                    // act == ia on g=0 lanes
  const float e2 = fast_exp2(ct);
  const float tc = fmaf(fast_rcp(1.0f + e2), 2.0f, -1.0f);   // tanh(c)
  h = oa * tc;
  // pack f16 pair (h_self, h_lane+4): row_shl:4 + pkrtz
  const int hpart = __builtin_amdgcn_update_dpp(
      0, __float_as_int(h), 0x104, 0xF, 0xF, true);
  hpk = __builtin_bit_cast(unsigned,
      __builtin_amdgcn_cvt_pkrtz(h, __int_as_float(hpart)));
}

// One bidirectional-LSTM layer. grid = 256 blocks (b*2+dir), block = 192 (3 waves).
// One chain per consumer wave (only per-step latency matters: 256 chains/256 CUs).
// Ring layout [group][swizzled-lane][4]: lane dword offset = 4*lane + 4*(lane>>3)
// keeps 16B alignment AND spreads each 8-lane b128 phase across 32 distinct banks
// (counter-verified in R8: conflicts 1.8M -> 0.82M).
// Wave 0: consumer. Waves 1,2: phase A produce xW; phase B drain h (chunk c-2).
template<int IN, bool LAST>
__global__ __launch_bounds__(192, 1) void bilstm_layer(
    const float* __restrict__ x,     // (B,T,IN)
    const float* __restrict__ Wih,   // (2,64,IN)
    const float* __restrict__ Whh,   // (2,64,16)
    const float* __restrict__ bias,  // (2,64)
    float* __restrict__ out)         // (B,T,32) or (B,256,32) if LAST
{
  constexpr int T = 2048;
  constexpr int C = 64;          // ring chunk (steps)
  constexpr int NG = C / 4;      // groups per chunk (16)
  constexpr int GS = 288;        // group stride in dwords
  constexpr int NCH = T / C;
  constexpr int NSLOT = NCH + 2; // xW produce -> consume -> h drain
  constexpr int NV4 = IN / 4;
  const int b    = blockIdx.x >> 1;
  const int dir  = blockIdx.x & 1;
  const int tid  = threadIdx.x;
  const int wave = tid >> 6;
  const int lane = tid & 63;
  const int g = lane & 3;
  const int r = g * 16 + (lane >> 2);
  const int dl = lane * 4 + ((lane >> 3) << 2);   // swizzled dword offset
  const float ksc = (g == 2) ? 2.0f * LOG2E : LOG2E;

  __shared__ float ring [2][(NG + 1) * GS];  // xW staging (+1 group: prefetch pad)
  __shared__ float ring2[2][NG * GS];        // h staging (consumer -> drainers)

  if (wave >= 1) {
    // ---------------- producers ----------------
    const int pw = wave - 1;
    float wih[IN];
    const float* wr = Wih + (size_t)(dir * 64 + r) * IN;
#pragma unroll
    for (int k = 0; k < IN; ++k) wih[k] = -ksc * wr[k];
    const float bneg = -ksc * bias[dir * 64 + r];
    const float* xb = x + (size_t)b * T * IN;
    const int sl = lane >> 4;    // h-drain: step sub-index 0..3
    const int jj = lane & 15;    // h-drain: hidden index
    const int dj = 16 * jj + ((jj >> 1) << 2);    // = swizzle of lane 4*jj
    for (int c = 0; c < NSLOT; ++c) {
      // phase A: produce xW(chunk c), groups [pw*8, pw*8+8)
      if (c < NCH) {
        const int tt0  = c * C;
        const int tmin = dir ? (T - C - tt0) : tt0;
        const float* src = xb + (size_t)(tmin + lane) * IN;
        float4 xr[NV4];
#pragma unroll
        for (int v = 0; v < NV4; ++v) xr[v] = *(const float4*)(src + 4 * v);
        float* buf = ring[c & 1] + dl;
        for (int mg = pw * 8; mg < pw * 8 + 8; ++mg) {
          float4 acc4;
          float* ap = &acc4.x;
#pragma unroll
          for (int u = 0; u < 4; ++u) {
            const int s   = mg * 4 + u;
            const int row = dir ? (C - 1 - s) : s;
            float a0 = bneg, a1 = 0.0f;
#pragma unroll
            for (int v = 0; v < NV4; ++v) {
              a0 = fmaf(rl(xr[v].x, row), wih[4 * v + 0], a0);
              a1 = fmaf(rl(xr[v].y, row), wih[4 * v + 1], a1);
              a0 = fmaf(rl(xr[v].z, row), wih[4 * v + 2], a0);
              a1 = fmaf(rl(xr[v].w, row), wih[4 * v + 3], a1);
            }
            ap[u] = a0 + a1;   // = -ksc*(Wih·x_t + b)
          }
          *(float4*)(buf + mg * GS) = acc4;        // ds_write_b128, de-conflicted
        }
      }
      // phase B: drain h(chunk c-2) to global
      if (c >= 2 && c - 2 < NCH) {
        const int d = c - 2;
        const float* r2 = ring2[d & 1];
        for (int s0 = pw * 32; s0 < pw * 32 + 32; s0 += 4) {
          const int s  = s0 + sl;
          const float hv = r2[(s >> 2) * GS + dj + (s & 3)];
          const int tt = d * C + s;
          const int t  = dir ? (T - 1 - tt) : tt;
          if (!LAST) {
            out[((size_t)b * T + t) * 32 + dir * 16 + jj] = hv;
          } else if ((t & 7) == 7) {
            out[((size_t)b * 256 + (t >> 3)) * 32 + dir * 16 + jj] = hv;
          }
        }
      }
      __syncthreads();
    }
  } else {
    // ---------------- consumer (recurrence) ----------------
    h2t w2[8];
    {
      const float* wr = Whh + (size_t)(dir * 64 + r) * 16;
#pragma unroll
      for (int p = 0; p < 8; ++p) {
        h2t w;
        w.x = (_Float16)(-ksc * wr[2 * p]);
        w.y = (_Float16)(-ksc * wr[2 * p + 1]);
        w2[p] = w;
      }
    }
    const float amul = (g == 2) ? -4.0f * LOG2E : 1.0f;
    const float aadd = (g == 2) ?  2.0f * LOG2E : 0.0f;
    float ct = 0.0f, h = 0.0f;
    unsigned hpk = 0;
    for (int c = 0; c < NSLOT; ++c) {
      if (c >= 1 && c <= NCH) {
        const float* bp = ring [(c - 1) & 1] + dl;
        float*       hb = ring2[(c - 1) & 1] + dl;
        float4 cur = *(const float4*)(bp);          // group 0
#pragma unroll 4
        for (int mg = 0; mg < NG; ++mg) {
          const float4 nxt = *(const float4*)(bp + (mg + 1) * GS);  // pad: safe
          float4 hv4;
          lstm_step(cur.x, w2, amul, aadd, hpk, ct, h); hv4.x = h;
          lstm_step(cur.y, w2, amul, aadd, hpk, ct, h); hv4.y = h;
          lstm_step(cur.z, w2, amul, aadd, hpk, ct, h); hv4.z = h;
          lstm_step(cur.w, w2, amul, aadd, hpk, ct, h); hv4.w = h;
          *(float4*)(hb + mg * GS) = hv4;           // ds_write_b128
          cur = nxt;
        }
      }
      __syncthreads();
    }
  }
}

// Precompute layer-0 xW for the unidirectional stack: xw0[b][t][g] = ub0[g] + uWih0[g]·x
__global__ __launch_bounds__(256) void uni_xw0(
    const float* __restrict__ dsb,    // (B,256,32)
    const float* __restrict__ uWih0,  // (4,32)
    const float* __restrict__ ub,     // (4,4) — row 0 used
    float* __restrict__ xw0)          // (B,256,4)
{
  const int b = blockIdx.x;
  const int t = threadIdx.x;
  const float* xp = dsb + ((size_t)b * 256 + t) * 32;
  float xv[32];
#pragma unroll
  for (int k = 0; k < 32; k += 4) {
    const float4 v = *(const float4*)(xp + k);
    xv[k] = v.x; xv[k + 1] = v.y; xv[k + 2] = v.z; xv[k + 3] = v.w;
  }
  float4 o;
  float* po = &o.x;
#pragma unroll
  for (int gg = 0; gg < 4; ++gg) {
    float a0 = ub[gg], a1 = 0.f;
#pragma unroll
    for (int k = 0; k < 32; k += 2) {
      a0 = fmaf(uWih0[gg * 32 + k],     xv[k],     a0);
      a1 = fmaf(uWih0[gg * 32 + k + 1], xv[k + 1], a1);
    }
    po[gg] = a0 + a1;
  }
  *(float4*)(xw0 + ((size_t)b * 256 + t) * 4) = o;
}

// Fused 4-layer unidirectional stack (HU=1), software-pipelined: iteration i
// steps l0@t=i, l1@t=i-1, l2@t=i-2, l3@t=i-3 — 4 independent cells per
// iteration = 4-way ILP in one wave. lane = batch element.
__global__ __launch_bounds__(64, 1) void uni_stack(
    const float* __restrict__ xw0,   // (B,256,4) pre-biased layer-0 xW
    const float* __restrict__ uWih,  // (3,4,1)
    const float* __restrict__ uWhh,  // (4,4,1)
    const float* __restrict__ ub,    // (4,4)
    float* __restrict__ out)         // (B,256)
{
  const int b = blockIdx.x * 64 + threadIdx.x;
  float whh[4][4], wih[3][4], bs[3][4];
#pragma unroll
  for (int l = 0; l < 4; ++l)
#pragma unroll
    for (int gg = 0; gg < 4; ++gg) whh[l][gg] = rfl(uWhh[l * 4 + gg]);
#pragma unroll
  for (int l = 0; l < 3; ++l)
#pragma unroll
    for (int gg = 0; gg < 4; ++gg) {
      wih[l][gg] = rfl(uWih[l * 4 + gg]);
      bs[l][gg]  = rfl(ub[(l + 1) * 4 + gg]);
    }
  float h[4] = {0, 0, 0, 0}, c[4] = {0, 0, 0, 0};
  const float4* xp = (const float4*)(xw0 + (size_t)b * 256 * 4);
  float* op = out + (size_t)b * 256;
  for (int i = 0; i < 256 + 3; ++i) {
    const float h0p = h[0], h1p = h[1], h2p = h[2];  // previous-iteration values
    if (i < 256) {
      const float4 xw = xp[i];
      const float i0 = sigf(fmaf(whh[0][0], h[0], xw.x));
      const float f0 = sigf(fmaf(whh[0][1], h[0], xw.y));
      const float g0 = tanhfast(fmaf(whh[0][2], h[0], xw.z));
      const float o0 = sigf(fmaf(whh[0][3], h[0], xw.w));
      c[0] = fmaf(f0, c[0], i0 * g0);
      h[0] = o0 * tanhfast(c[0]);
    }
    if (i >= 1 && i < 257) {
      const float pi  = fmaf(whh[1][0], h[1], fmaf(wih[0][0], h0p, bs[0][0]));
      const float pf  = fmaf(whh[1][1], h[1], fmaf(wih[0][1], h0p, bs[0][1]));
      const float pg  = fmaf(whh[1][2], h[1], fmaf(wih[0][2], h0p, bs[0][2]));
      const float po_ = fmaf(whh[1][3], h[1], fmaf(wih[0][3], h0p, bs[0][3]));
      const float il = sigf(pi), fl = sigf(pf), gl = tanhfast(pg), ol = sigf(po_);
      c[1] = fmaf(fl, c[1], il * gl);
      h[1] = ol * tanhfast(c[1]);
    }
    if (i >= 2 && i < 258) {
      const float pi  = fmaf(whh[2][0], h[2], fmaf(wih[1][0], h1p, bs[1][0]));
      const float pf  = fmaf(whh[2][1], h[2], fmaf(wih[1][1], h1p, bs[1][1]));
      const float pg  = fmaf(whh[2][2], h[2], fmaf(wih[1][2], h1p, bs[1][2]));
      const float po_ = fmaf(whh[2][3], h[2], fmaf(wih[1][3], h1p, bs[1][3]));
      const float il = sigf(pi), fl = sigf(pf), gl = tanhfast(pg), ol = sigf(po_);
      c[2] = fmaf(fl, c[2], il * gl);
      h[2] = ol * tanhfast(c[2]);
    }
    if (i >= 3) {
      const float pi  = fmaf(whh[3][0], h[3], fmaf(wih[2][0], h2p, bs[2][0]));
      const float pf  = fmaf(whh[3][1], h[3], fmaf(wih[2][1], h2p, bs[2][1]));
      const float pg  = fmaf(whh[3][2], h[3], fmaf(wih[2][2], h2p, bs[2][2]));
      const float po_ = fmaf(whh[3][3], h[3], fmaf(wih[2][3], h2p, bs[2][3]));
      const float il = sigf(pi), fl = sigf(pf), gl = tanhfast(pg), ol = sigf(po_);
      c[3] = fmaf(fl, c[3], il * gl);
      h[3] = ol * tanhfast(c[3]);
      op[i - 3] = h[3];
    }
  }
}

extern "C" void kernel_launch(void* const* d_in, const int* in_sizes, int n_in,
                              void* d_out, int out_size, void* d_ws, size_t ws_size,
                              hipStream_t stream)
{
  (void)in_sizes; (void)n_in; (void)out_size; (void)ws_size;
  const float* r_c_s = (const float*)d_in[0];
  const float* bWih0 = (const float*)d_in[1];
  const float* bWih  = (const float*)d_in[2];
  const float* bWhh  = (const float*)d_in[3];
  const float* bb    = (const float*)d_in[4];
  const float* uWih0 = (const float*)d_in[5];
  const float* uWih  = (const float*)d_in[6];
  const float* uWhh  = (const float*)d_in[7];
  const float* ub    = (const float*)d_in[8];
  float* outp = (float*)d_out;

  // workspace layout (floats): two (B,T,32) ping-pong, (B,256,32) downsample, (B,256,4) uni-xW
  float* x0  = (float*)d_ws;
  float* x1  = x0  + (size_t)128 * 2048 * 32;
  float* dsb = x1  + (size_t)128 * 2048 * 32;
  float* xw0 = dsb + (size_t)128 * 256 * 32;

  const dim3 grid(256), block(192);
  bilstm_layer<24, false><<<grid, block, 0, stream>>>(r_c_s, bWih0,               bWhh + 0,               bb + 0,          x0);
  bilstm_layer<32, false><<<grid, block, 0, stream>>>(x0,    bWih + 0 * 2*64*32,  bWhh + 1 * 2*64*16,     bb + 1 * 2*64,   x1);
  bilstm_layer<32, false><<<grid, block, 0, stream>>>(x1,    bWih + 1 * 2*64*32,  bWhh + 2 * 2*64*16,     bb + 2 * 2*64,   x0);
  bilstm_layer<32, true ><<<grid, block, 0, stream>>>(x0,    bWih + 2 * 2*64*32,  bWhh + 3 * 2*64*16,     bb + 3 * 2*64,   dsb);
  uni_xw0 <<<dim3(128), dim3(256), 0, stream>>>(dsb, uWih0, ub, xw0);
  uni_stack<<<dim3(2),   dim3(64),  0, stream>>>(xw0, uWih, uWhh, ub, outp);
}

// Round 10
// 1009.974 us; speedup vs baseline: 1.0810x; 1.0103x over previous
//
#include <hip/hip_runtime.h>

#define LOG2E 1.4426950408889634f

typedef _Float16 h2t __attribute__((ext_vector_type(2)));

// broadcast lane `srclane`'s value to all lanes via v_readlane (SGPR result).
__device__ __forceinline__ float rl(float v, int srclane) {
  return __int_as_float(__builtin_amdgcn_readlane(__float_as_int(v), srclane));
}
__device__ __forceinline__ unsigned rlu(unsigned v, int srclane) {
  return (unsigned)__builtin_amdgcn_readlane((int)v, srclane);
}
__device__ __forceinline__ float rfl(float v) {
  return __int_as_float(__builtin_amdgcn_readfirstlane(__float_as_int(v)));
}

// quad broadcast via DPP quad_perm
template<int CTL>
__device__ __forceinline__ float qb(float v) {
  return __int_as_float(__builtin_amdgcn_update_dpp(0, __float_as_int(v), CTL, 0xF, 0xF, true));
}

__device__ __forceinline__ float fast_rcp(float x)  { return __builtin_amdgcn_rcpf(x); }
__device__ __forceinline__ float fast_exp2(float x) { return __builtin_amdgcn_exp2f(x); }

__device__ __forceinline__ float sigf(float x) {
  return fast_rcp(1.0f + fast_exp2(-LOG2E * x));
}
__device__ __forceinline__ float tanhfast(float x) {
  return fmaf(fast_rcp(1.0f + fast_exp2(-2.0f * LOG2E * x)), 2.0f, -1.0f);
}

#if defined(__has_builtin)
#if __has_builtin(__builtin_amdgcn_fdot2)
#define USE_FDOT2 1
#endif
#endif

__device__ __forceinline__ float fd2(unsigned q, h2t w, float acc) {
#if defined(USE_FDOT2)
  return __builtin_amdgcn_fdot2(__builtin_bit_cast(h2t, q), w, acc, false);
#else
  h2t a = __builtin_elementwise_fma(__builtin_bit_cast(h2t, q), w,
                                    (h2t){(_Float16)0, (_Float16)0});
  return acc + (float)a.x + (float)a.y;
#endif
}

// one LSTM recurrence step (lane layout: r = g*16+j, g=lane&3).
// hpk holds the f16 pair (h_{2p}, h_{2p+1}) valid on lanes 8p.
// R10 chain surgery vs R9:
//  - fdot2 tree depth 2 (chain 30->24 cyc, +2 instrs)
//  - ig reassociation: ig = fmaf(-4L*sgm, ga_raw, 2L*sgm) — muls run parallel
//    with the DPP instead of an act-fma BEFORE it (ct path -6 cyc)
//  - h = fmaf(2*oa, rcp(1+e2), -oa) — folds tanh-fma and oa-mul (h path -6 cyc)
// All exact reassociations. Gates i,f,o need NO act transform (sigmoid identity);
// only g's tanh scale is applied, post-broadcast.
__device__ __forceinline__ void lstm_step(float pre, const h2t* __restrict__ w2,
                                          unsigned& hpk, float& ct, float& h) {
  const unsigned q0 = rlu(hpk,  0);
  const unsigned q1 = rlu(hpk,  8);
  const unsigned q4 = rlu(hpk, 32);
  const unsigned q5 = rlu(hpk, 40);
  const unsigned q2 = rlu(hpk, 16);
  const unsigned q3 = rlu(hpk, 24);
  const unsigned q6 = rlu(hpk, 48);
  const unsigned q7 = rlu(hpk, 56);
  float c0 = fd2(q0, w2[0], pre);
  float c1 = fd2(q1, w2[1], 0.f);
  float c2 = fd2(q4, w2[4], 0.f);
  float c3 = fd2(q5, w2[5], 0.f);
  c0 = fd2(q2, w2[2], c0);
  c1 = fd2(q3, w2[3], c1);
  c2 = fd2(q6, w2[6], c2);
  c3 = fd2(q7, w2[7], c3);
  const float m = (c0 + c1) + (c2 + c3);          // = -ksc * preact
  const float e   = fast_exp2(m);
  const float sgm = fast_rcp(1.0f + e);           // sigmoid(ksc*P) — all gates raw
  const float m4  = sgm * (-4.0f * LOG2E);        // own-lane (== -4L*ia on g0)
  const float t2  = sgm * ( 2.0f * LOG2E);        // own-lane (==  2L*ia on g0)
  const float fa = qb<0x55>(sgm);
  const float gr = qb<0xAA>(sgm);                 // raw sigmoid of g-gate (2x arg)
  const float oa = qb<0xFF>(sgm);
  const float ig = fmaf(m4, gr, t2);              // = ia * (-2log2e * tanh(g))
  ct = fmaf(fa, ct, ig);                          // ct = -2log2e * c
  const float e2 = fast_exp2(ct);
  const float rv = fast_rcp(1.0f + e2);
  const float oa2 = oa + oa;                      // off-chain
  h = fmaf(oa2, rv, -oa);                         // = oa * tanh(c)
  // pack f16 pair (h_self, h_lane+4): row_shl:4 + pkrtz
  const int hpart = __builtin_amdgcn_update_dpp(
      0, __float_as_int(h), 0x104, 0xF, 0xF, true);
  hpk = __builtin_bit_cast(unsigned,
      __builtin_amdgcn_cvt_pkrtz(h, __int_as_float(hpart)));
}

// One bidirectional-LSTM layer. grid = 256 blocks (b*2+dir), block = 192 (3 waves).
// One chain per consumer wave (only per-step latency matters: 256 chains/256 CUs).
// Ring layout [group][swizzled-lane][4]: lane dword offset = 4*lane + 4*(lane>>3)
// (counter-verified de-conflict, R8). Wave 0: consumer. Waves 1,2: produce xW;
// drain h (chunk c-2).
template<int IN, bool LAST>
__global__ __launch_bounds__(192, 1) void bilstm_layer(
    const float* __restrict__ x,     // (B,T,IN)
    const float* __restrict__ Wih,   // (2,64,IN)
    const float* __restrict__ Whh,   // (2,64,16)
    const float* __restrict__ bias,  // (2,64)
    float* __restrict__ out)         // (B,T,32) or (B,256,32) if LAST
{
  constexpr int T = 2048;
  constexpr int C = 64;          // ring chunk (steps)
  constexpr int NG = C / 4;      // groups per chunk (16)
  constexpr int GS = 288;        // group stride in dwords
  constexpr int NCH = T / C;
  constexpr int NSLOT = NCH + 2; // xW produce -> consume -> h drain
  constexpr int NV4 = IN / 4;
  const int b    = blockIdx.x >> 1;
  const int dir  = blockIdx.x & 1;
  const int tid  = threadIdx.x;
  const int wave = tid >> 6;
  const int lane = tid & 63;
  const int g = lane & 3;
  const int r = g * 16 + (lane >> 2);
  const int dl = lane * 4 + ((lane >> 3) << 2);   // swizzled dword offset
  const float ksc = (g == 2) ? 2.0f * LOG2E : LOG2E;

  __shared__ float ring [2][(NG + 1) * GS];  // xW staging (+1 group: prefetch pad)
  __shared__ float ring2[2][NG * GS];        // h staging (consumer -> drainers)

  if (wave >= 1) {
    // ---------------- producers ----------------
    const int pw = wave - 1;
    float wih[IN];
    const float* wr = Wih + (size_t)(dir * 64 + r) * IN;
#pragma unroll
    for (int k = 0; k < IN; ++k) wih[k] = -ksc * wr[k];
    const float bneg = -ksc * bias[dir * 64 + r];
    const float* xb = x + (size_t)b * T * IN;
    const int sl = lane >> 4;    // h-drain: step sub-index 0..3
    const int jj = lane & 15;    // h-drain: hidden index
    const int dj = 16 * jj + ((jj >> 1) << 2);    // = swizzle of lane 4*jj
    for (int c = 0; c < NSLOT; ++c) {
      // phase A: produce xW(chunk c), groups [pw*8, pw*8+8)
      if (c < NCH) {
        const int tt0  = c * C;
        const int tmin = dir ? (T - C - tt0) : tt0;
        const float* src = xb + (size_t)(tmin + lane) * IN;
        float4 xr[NV4];
#pragma unroll
        for (int v = 0; v < NV4; ++v) xr[v] = *(const float4*)(src + 4 * v);
        float* buf = ring[c & 1] + dl;
        for (int mg = pw * 8; mg < pw * 8 + 8; ++mg) {
          float4 acc4;
          float* ap = &acc4.x;
#pragma unroll
          for (int u = 0; u < 4; ++u) {
            const int s   = mg * 4 + u;
            const int row = dir ? (C - 1 - s) : s;
            float a0 = bneg, a1 = 0.0f;
#pragma unroll
            for (int v = 0; v < NV4; ++v) {
              a0 = fmaf(rl(xr[v].x, row), wih[4 * v + 0], a0);
              a1 = fmaf(rl(xr[v].y, row), wih[4 * v + 1], a1);
              a0 = fmaf(rl(xr[v].z, row), wih[4 * v + 2], a0);
              a1 = fmaf(rl(xr[v].w, row), wih[4 * v + 3], a1);
            }
            ap[u] = a0 + a1;   // = -ksc*(Wih·x_t + b)
          }
          *(float4*)(buf + mg * GS) = acc4;        // ds_write_b128, de-conflicted
        }
      }
      // phase B: drain h(chunk c-2) to global
      if (c >= 2 && c - 2 < NCH) {
        const int d = c - 2;
        const float* r2 = ring2[d & 1];
        for (int s0 = pw * 32; s0 < pw * 32 + 32; s0 += 4) {
          const int s  = s0 + sl;
          const float hv = r2[(s >> 2) * GS + dj + (s & 3)];
          const int tt = d * C + s;
          const int t  = dir ? (T - 1 - tt) : tt;
          if (!LAST) {
            out[((size_t)b * T + t) * 32 + dir * 16 + jj] = hv;
          } else if ((t & 7) == 7) {
            out[((size_t)b * 256 + (t >> 3)) * 32 + dir * 16 + jj] = hv;
          }
        }
      }
      __syncthreads();
    }
  } else {
    // ---------------- consumer (recurrence) ----------------
    h2t w2[8];
    {
      const float* wr = Whh + (size_t)(dir * 64 + r) * 16;
#pragma unroll
      for (int p = 0; p < 8; ++p) {
        h2t w;
        w.x = (_Float16)(-ksc * wr[2 * p]);
        w.y = (_Float16)(-ksc * wr[2 * p + 1]);
        w2[p] = w;
      }
    }
    float ct = 0.0f, h = 0.0f;
    unsigned hpk = 0;
    for (int c = 0; c < NSLOT; ++c) {
      if (c >= 1 && c <= NCH) {
        const float* bp = ring [(c - 1) & 1] + dl;
        float*       hb = ring2[(c - 1) & 1] + dl;
        float4 cur = *(const float4*)(bp);          // group 0
#pragma unroll 4
        for (int mg = 0; mg < NG; ++mg) {
          const float4 nxt = *(const float4*)(bp + (mg + 1) * GS);  // pad: safe
          float4 hv4;
          lstm_step(cur.x, w2, hpk, ct, h); hv4.x = h;
          lstm_step(cur.y, w2, hpk, ct, h); hv4.y = h;
          lstm_step(cur.z, w2, hpk, ct, h); hv4.z = h;
          lstm_step(cur.w, w2, hpk, ct, h); hv4.w = h;
          *(float4*)(hb + mg * GS) = hv4;           // ds_write_b128
          cur = nxt;
        }
      }
      __syncthreads();
    }
  }
}

// Precompute layer-0 xW for the unidirectional stack: xw0[b][t][g] = ub0[g] + uWih0[g]·x
__global__ __launch_bounds__(256) void uni_xw0(
    const float* __restrict__ dsb,    // (B,256,32)
    const float* __restrict__ uWih0,  // (4,32)
    const float* __restrict__ ub,     // (4,4) — row 0 used
    float* __restrict__ xw0)          // (B,256,4)
{
  const int b = blockIdx.x;
  const int t = threadIdx.x;
  const float* xp = dsb + ((size_t)b * 256 + t) * 32;
  float xv[32];
#pragma unroll
  for (int k = 0; k < 32; k += 4) {
    const float4 v = *(const float4*)(xp + k);
    xv[k] = v.x; xv[k + 1] = v.y; xv[k + 2] = v.z; xv[k + 3] = v.w;
  }
  float4 o;
  float* po = &o.x;
#pragma unroll
  for (int gg = 0; gg < 4; ++gg) {
    float a0 = ub[gg], a1 = 0.f;
#pragma unroll
    for (int k = 0; k < 32; k += 2) {
      a0 = fmaf(uWih0[gg * 32 + k],     xv[k],     a0);
      a1 = fmaf(uWih0[gg * 32 + k + 1], xv[k + 1], a1);
    }
    po[gg] = a0 + a1;
  }
  *(float4*)(xw0 + ((size_t)b * 256 + t) * 4) = o;
}

// Fused 4-layer unidirectional stack (HU=1), software-pipelined (4-way ILP),
// with 1-ahead xw prefetch: R9 had a DEPENDENT global load (xp[i]) heading
// every iteration (~300 cyc exposed); cur/nxt gives one iteration of slack.
__global__ __launch_bounds__(64, 1) void uni_stack(
    const float* __restrict__ xw0,   // (B,256,4) pre-biased layer-0 xW
    const float* __restrict__ uWih,  // (3,4,1)
    const float* __restrict__ uWhh,  // (4,4,1)
    const float* __restrict__ ub,    // (4,4)
    float* __restrict__ out)         // (B,256)
{
  const int b = blockIdx.x * 64 + threadIdx.x;
  float whh[4][4], wih[3][4], bs[3][4];
#pragma unroll
  for (int l = 0; l < 4; ++l)
#pragma unroll
    for (int gg = 0; gg < 4; ++gg) whh[l][gg] = rfl(uWhh[l * 4 + gg]);
#pragma unroll
  for (int l = 0; l < 3; ++l)
#pragma unroll
    for (int gg = 0; gg < 4; ++gg) {
      wih[l][gg] = rfl(uWih[l * 4 + gg]);
      bs[l][gg]  = rfl(ub[(l + 1) * 4 + gg]);
    }
  float h[4] = {0, 0, 0, 0}, c[4] = {0, 0, 0, 0};
  const float4* xp = (const float4*)(xw0 + (size_t)b * 256 * 4);
  float* op = out + (size_t)b * 256;
  float4 cur = xp[0];
  for (int i = 0; i < 256 + 3; ++i) {
    const float4 nxt = xp[(i < 255) ? (i + 1) : 255];   // prefetch next
    const float h0p = h[0], h1p = h[1], h2p = h[2];     // previous-iteration values
    if (i < 256) {
      const float i0 = sigf(fmaf(whh[0][0], h[0], cur.x));
      const float f0 = sigf(fmaf(whh[0][1], h[0], cur.y));
      const float g0 = tanhfast(fmaf(whh[0][2], h[0], cur.z));
      const float o0 = sigf(fmaf(whh[0][3], h[0], cur.w));
      c[0] = fmaf(f0, c[0], i0 * g0);
      h[0] = o0 * tanhfast(c[0]);
    }
    if (i >= 1 && i < 257) {
      const float pi  = fmaf(whh[1][0], h[1], fmaf(wih[0][0], h0p, bs[0][0]));
      const float pf  = fmaf(whh[1][1], h[1], fmaf(wih[0][1], h0p, bs[0][1]));
      const float pg  = fmaf(whh[1][2], h[1], fmaf(wih[0][2], h0p, bs[0][2]));
      const float po_ = fmaf(whh[1][3], h[1], fmaf(wih[0][3], h0p, bs[0][3]));
      const float il = sigf(pi), fl = sigf(pf), gl = tanhfast(pg), ol = sigf(po_);
      c[1] = fmaf(fl, c[1], il * gl);
      h[1] = ol * tanhfast(c[1]);
    }
    if (i >= 2 && i < 258) {
      const float pi  = fmaf(whh[2][0], h[2], fmaf(wih[1][0], h1p, bs[1][0]));
      const float pf  = fmaf(whh[2][1], h[2], fmaf(wih[1][1], h1p, bs[1][1]));
      const float pg  = fmaf(whh[2][2], h[2], fmaf(wih[1][2], h1p, bs[1][2]));
      const float po_ = fmaf(whh[2][3], h[2], fmaf(wih[1][3], h1p, bs[1][3]));
      const float il = sigf(pi), fl = sigf(pf), gl = tanhfast(pg), ol = sigf(po_);
      c[2] = fmaf(fl, c[2], il * gl);
      h[2] = ol * tanhfast(c[2]);
    }
    if (i >= 3) {
      const float pi  = fmaf(whh[3][0], h[3], fmaf(wih[2][0], h2p, bs[2][0]));
      const float pf  = fmaf(whh[3][1], h[3], fmaf(wih[2][1], h2p, bs[2][1]));
      const float pg  = fmaf(whh[3][2], h[3], fmaf(wih[2][2], h2p, bs[2][2]));
      const float po_ = fmaf(whh[3][3], h[3], fmaf(wih[2][3], h2p, bs[2][3]));
      const float il = sigf(pi), fl = sigf(pf), gl = tanhfast(pg), ol = sigf(po_);
      c[3] = fmaf(fl, c[3], il * gl);
      h[3] = ol * tanhfast(c[3]);
      op[i - 3] = h[3];
    }
    cur = nxt;
  }
}

extern "C" void kernel_launch(void* const* d_in, const int* in_sizes, int n_in,
                              void* d_out, int out_size, void* d_ws, size_t ws_size,
                              hipStream_t stream)
{
  (void)in_sizes; (void)n_in; (void)out_size; (void)ws_size;
  const float* r_c_s = (const float*)d_in[0];
  const float* bWih0 = (const float*)d_in[1];
  const float* bWih  = (const float*)d_in[2];
  const float* bWhh  = (const float*)d_in[3];
  const float* bb    = (const float*)d_in[4];
  const float* uWih0 = (const float*)d_in[5];
  const float* uWih  = (const float*)d_in[6];
  const float* uWhh  = (const float*)d_in[7];
  const float* ub    = (const float*)d_in[8];
  float* outp = (float*)d_out;

  // workspace layout (floats): two (B,T,32) ping-pong, (B,256,32) downsample, (B,256,4) uni-xW
  float* x0  = (float*)d_ws;
  float* x1  = x0  + (size_t)128 * 2048 * 32;
  float* dsb = x1  + (size_t)128 * 2048 * 32;
  float* xw0 = dsb + (size_t)128 * 256 * 32;

  const dim3 grid(256), block(192);
  bilstm_layer<24, false><<<grid, block, 0, stream>>>(r_c_s, bWih0,               bWhh + 0,               bb + 0,          x0);
  bilstm_layer<32, false><<<grid, block, 0, stream>>>(x0,    bWih + 0 * 2*64*32,  bWhh + 1 * 2*64*16,     bb + 1 * 2*64,   x1);
  bilstm_layer<32, false><<<grid, block, 0, stream>>>(x1,    bWih + 1 * 2*64*32,  bWhh + 2 * 2*64*16,     bb + 2 * 2*64,   x0);
  bilstm_layer<32, true ><<<grid, block, 0, stream>>>(x0,    bWih + 2 * 2*64*32,  bWhh + 3 * 2*64*16,     bb + 3 * 2*64,   dsb);
  uni_xw0 <<<dim3(128), dim3(256), 0, stream>>>(dsb, uWih0, ub, xw0);
  uni_stack<<<dim3(2),   dim3(64),  0, stream>>>(xw0, uWih, uWhh, ub, outp);
}

// Round 11
// 900.158 us; speedup vs baseline: 1.2128x; 1.1220x over previous
//
#include <hip/hip_runtime.h>

#define LOG2E 1.4426950408889634f

typedef _Float16 h2t __attribute__((ext_vector_type(2)));

// broadcast lane `srclane`'s value to all lanes via v_readlane (SGPR result).
__device__ __forceinline__ float rl(float v, int srclane) {
  return __int_as_float(__builtin_amdgcn_readlane(__float_as_int(v), srclane));
}
__device__ __forceinline__ unsigned rlu(unsigned v, int srclane) {
  return (unsigned)__builtin_amdgcn_readlane((int)v, srclane);
}
__device__ __forceinline__ float rfl(float v) {
  return __int_as_float(__builtin_amdgcn_readfirstlane(__float_as_int(v)));
}

// quad broadcast via DPP quad_perm
template<int CTL>
__device__ __forceinline__ float qb(float v) {
  return __int_as_float(__builtin_amdgcn_update_dpp(0, __float_as_int(v), CTL, 0xF, 0xF, true));
}

__device__ __forceinline__ float fast_rcp(float x)  { return __builtin_amdgcn_rcpf(x); }
__device__ __forceinline__ float fast_exp2(float x) { return __builtin_amdgcn_exp2f(x); }

__device__ __forceinline__ float sigf(float x) {
  return fast_rcp(1.0f + fast_exp2(-LOG2E * x));
}
__device__ __forceinline__ float tanhfast(float x) {
  return fmaf(fast_rcp(1.0f + fast_exp2(-2.0f * LOG2E * x)), 2.0f, -1.0f);
}

#if defined(__has_builtin)
#if __has_builtin(__builtin_amdgcn_fdot2)
#define USE_FDOT2 1
#endif
#endif

__device__ __forceinline__ float fd2(unsigned q, h2t w, float acc) {
#if defined(USE_FDOT2)
  return __builtin_amdgcn_fdot2(__builtin_bit_cast(h2t, q), w, acc, false);
#else
  h2t a = __builtin_elementwise_fma(__builtin_bit_cast(h2t, q), w,
                                    (h2t){(_Float16)0, (_Float16)0});
  return acc + (float)a.x + (float)a.y;
#endif
}

// one LSTM recurrence step (lane layout: r = g*16+j, g=lane&3). R10 version
// (206 µs/layer — at the structure's measured floor; R9 and R10 variants tie).
__device__ __forceinline__ void lstm_step(float pre, const h2t* __restrict__ w2,
                                          unsigned& hpk, float& ct, float& h) {
  const unsigned q0 = rlu(hpk,  0);
  const unsigned q1 = rlu(hpk,  8);
  const unsigned q4 = rlu(hpk, 32);
  const unsigned q5 = rlu(hpk, 40);
  const unsigned q2 = rlu(hpk, 16);
  const unsigned q3 = rlu(hpk, 24);
  const unsigned q6 = rlu(hpk, 48);
  const unsigned q7 = rlu(hpk, 56);
  float c0 = fd2(q0, w2[0], pre);
  float c1 = fd2(q1, w2[1], 0.f);
  float c2 = fd2(q4, w2[4], 0.f);
  float c3 = fd2(q5, w2[5], 0.f);
  c0 = fd2(q2, w2[2], c0);
  c1 = fd2(q3, w2[3], c1);
  c2 = fd2(q6, w2[6], c2);
  c3 = fd2(q7, w2[7], c3);
  const float m = (c0 + c1) + (c2 + c3);          // = -ksc * preact
  const float e   = fast_exp2(m);
  const float sgm = fast_rcp(1.0f + e);           // sigmoid(ksc*P) — all gates raw
  const float m4  = sgm * (-4.0f * LOG2E);        // own-lane (== -4L*ia on g0)
  const float t2  = sgm * ( 2.0f * LOG2E);        // own-lane (==  2L*ia on g0)
  const float fa = qb<0x55>(sgm);
  const float gr = qb<0xAA>(sgm);                 // raw sigmoid of g-gate (2x arg)
  const float oa = qb<0xFF>(sgm);
  const float ig = fmaf(m4, gr, t2);              // = ia * (-2log2e * tanh(g))
  ct = fmaf(fa, ct, ig);                          // ct = -2log2e * c
  const float e2 = fast_exp2(ct);
  const float rv = fast_rcp(1.0f + e2);
  const float oa2 = oa + oa;                      // off-chain
  h = fmaf(oa2, rv, -oa);                         // = oa * tanh(c)
  // pack f16 pair (h_self, h_lane+4): row_shl:4 + pkrtz
  const int hpart = __builtin_amdgcn_update_dpp(
      0, __float_as_int(h), 0x104, 0xF, 0xF, true);
  hpk = __builtin_bit_cast(unsigned,
      __builtin_amdgcn_cvt_pkrtz(h, __int_as_float(hpart)));
}

// One bidirectional-LSTM layer. grid = 256 blocks (b*2+dir), block = 192 (3 waves).
// One chain per consumer wave; ring layout [group][swizzled-lane][4] (R8-verified
// de-conflict). Wave 0: consumer. Waves 1,2: produce xW; drain h (chunk c-2).
template<int IN, bool LAST>
__global__ __launch_bounds__(192, 1) void bilstm_layer(
    const float* __restrict__ x,     // (B,T,IN)
    const float* __restrict__ Wih,   // (2,64,IN)
    const float* __restrict__ Whh,   // (2,64,16)
    const float* __restrict__ bias,  // (2,64)
    float* __restrict__ out)         // (B,T,32) or (B,256,32) if LAST
{
  constexpr int T = 2048;
  constexpr int C = 64;          // ring chunk (steps)
  constexpr int NG = C / 4;      // groups per chunk (16)
  constexpr int GS = 288;        // group stride in dwords
  constexpr int NCH = T / C;
  constexpr int NSLOT = NCH + 2; // xW produce -> consume -> h drain
  constexpr int NV4 = IN / 4;
  const int b    = blockIdx.x >> 1;
  const int dir  = blockIdx.x & 1;
  const int tid  = threadIdx.x;
  const int wave = tid >> 6;
  const int lane = tid & 63;
  const int g = lane & 3;
  const int r = g * 16 + (lane >> 2);
  const int dl = lane * 4 + ((lane >> 3) << 2);   // swizzled dword offset
  const float ksc = (g == 2) ? 2.0f * LOG2E : LOG2E;

  __shared__ float ring [2][(NG + 1) * GS];  // xW staging (+1 group: prefetch pad)
  __shared__ float ring2[2][NG * GS];        // h staging (consumer -> drainers)

  if (wave >= 1) {
    // ---------------- producers ----------------
    const int pw = wave - 1;
    float wih[IN];
    const float* wr = Wih + (size_t)(dir * 64 + r) * IN;
#pragma unroll
    for (int k = 0; k < IN; ++k) wih[k] = -ksc * wr[k];
    const float bneg = -ksc * bias[dir * 64 + r];
    const float* xb = x + (size_t)b * T * IN;
    const int sl = lane >> 4;    // h-drain: step sub-index 0..3
    const int jj = lane & 15;    // h-drain: hidden index
    const int dj = 16 * jj + ((jj >> 1) << 2);    // = swizzle of lane 4*jj
    for (int c = 0; c < NSLOT; ++c) {
      // phase A: produce xW(chunk c), groups [pw*8, pw*8+8)
      if (c < NCH) {
        const int tt0  = c * C;
        const int tmin = dir ? (T - C - tt0) : tt0;
        const float* src = xb + (size_t)(tmin + lane) * IN;
        float4 xr[NV4];
#pragma unroll
        for (int v = 0; v < NV4; ++v) xr[v] = *(const float4*)(src + 4 * v);
        float* buf = ring[c & 1] + dl;
        for (int mg = pw * 8; mg < pw * 8 + 8; ++mg) {
          float4 acc4;
          float* ap = &acc4.x;
#pragma unroll
          for (int u = 0; u < 4; ++u) {
            const int s   = mg * 4 + u;
            const int row = dir ? (C - 1 - s) : s;
            float a0 = bneg, a1 = 0.0f;
#pragma unroll
            for (int v = 0; v < NV4; ++v) {
              a0 = fmaf(rl(xr[v].x, row), wih[4 * v + 0], a0);
              a1 = fmaf(rl(xr[v].y, row), wih[4 * v + 1], a1);
              a0 = fmaf(rl(xr[v].z, row), wih[4 * v + 2], a0);
              a1 = fmaf(rl(xr[v].w, row), wih[4 * v + 3], a1);
            }
            ap[u] = a0 + a1;   // = -ksc*(Wih·x_t + b)
          }
          *(float4*)(buf + mg * GS) = acc4;        // ds_write_b128, de-conflicted
        }
      }
      // phase B: drain h(chunk c-2) to global
      if (c >= 2 && c - 2 < NCH) {
        const int d = c - 2;
        const float* r2 = ring2[d & 1];
        for (int s0 = pw * 32; s0 < pw * 32 + 32; s0 += 4) {
          const int s  = s0 + sl;
          const float hv = r2[(s >> 2) * GS + dj + (s & 3)];
          const int tt = d * C + s;
          const int t  = dir ? (T - 1 - tt) : tt;
          if (!LAST) {
            out[((size_t)b * T + t) * 32 + dir * 16 + jj] = hv;
          } else if ((t & 7) == 7) {
            out[((size_t)b * 256 + (t >> 3)) * 32 + dir * 16 + jj] = hv;
          }
        }
      }
      __syncthreads();
    }
  } else {
    // ---------------- consumer (recurrence) ----------------
    h2t w2[8];
    {
      const float* wr = Whh + (size_t)(dir * 64 + r) * 16;
#pragma unroll
      for (int p = 0; p < 8; ++p) {
        h2t w;
        w.x = (_Float16)(-ksc * wr[2 * p]);
        w.y = (_Float16)(-ksc * wr[2 * p + 1]);
        w2[p] = w;
      }
    }
    float ct = 0.0f, h = 0.0f;
    unsigned hpk = 0;
    for (int c = 0; c < NSLOT; ++c) {
      if (c >= 1 && c <= NCH) {
        const float* bp = ring [(c - 1) & 1] + dl;
        float*       hb = ring2[(c - 1) & 1] + dl;
        float4 cur = *(const float4*)(bp);          // group 0
#pragma unroll 4
        for (int mg = 0; mg < NG; ++mg) {
          const float4 nxt = *(const float4*)(bp + (mg + 1) * GS);  // pad: safe
          float4 hv4;
          lstm_step(cur.x, w2, hpk, ct, h); hv4.x = h;
          lstm_step(cur.y, w2, hpk, ct, h); hv4.y = h;
          lstm_step(cur.z, w2, hpk, ct, h); hv4.z = h;
          lstm_step(cur.w, w2, hpk, ct, h); hv4.w = h;
          *(float4*)(hb + mg * GS) = hv4;           // ds_write_b128
          cur = nxt;
        }
      }
      __syncthreads();
    }
  }
}

// Precompute layer-0 xW for the unidirectional stack, TRANSPOSED (t-major):
// xw0T[t][b][g] = ub0[g] + uWih0[g]·dsb[b][t][:]. t-major makes the pipeline
// kernel's per-step load lane-coalesced (lane=batch, consecutive 16B).
__global__ __launch_bounds__(256) void uni_xw0(
    const float* __restrict__ dsb,    // (B,256,32)
    const float* __restrict__ uWih0,  // (4,32)
    const float* __restrict__ ub,     // (4,4) — row 0 used
    float* __restrict__ xw0T)         // (256,B,4)
{
  const int b = blockIdx.x;
  const int t = threadIdx.x;
  const float* xp = dsb + ((size_t)b * 256 + t) * 32;
  float xv[32];
#pragma unroll
  for (int k = 0; k < 32; k += 4) {
    const float4 v = *(const float4*)(xp + k);
    xv[k] = v.x; xv[k + 1] = v.y; xv[k + 2] = v.z; xv[k + 3] = v.w;
  }
  float4 o;
  float* po = &o.x;
#pragma unroll
  for (int gg = 0; gg < 4; ++gg) {
    float a0 = ub[gg], a1 = 0.f;
#pragma unroll
    for (int k = 0; k < 32; k += 2) {
      a0 = fmaf(uWih0[gg * 32 + k],     xv[k],     a0);
      a1 = fmaf(uWih0[gg * 32 + k + 1], xv[k + 1], a1);
    }
    po[gg] = a0 + a1;
  }
  ((float4*)xw0T)[t * 128 + b] = o;
}

// Fused 4-layer unidirectional stack (HU=1), LAYER-PIPELINED across 4 waves
// (bilstm-proven producer/consumer pattern): wave l = layer l, lane = batch.
// Chunked (C=8 steps) double-buffered LDS h-rings; wave l processes chunk c in
// slot c+l; barrier per slot. Each wave sits on its own SIMD and runs its own
// recurrence — replaces R10's single-wave 259-iteration serialization.
__global__ __launch_bounds__(256, 1) void uni_stack_pipe(
    const float* __restrict__ xw0T,  // (256,B,4) pre-biased layer-0 xW, t-major
    const float* __restrict__ uWih,  // (3,4,1)
    const float* __restrict__ uWhh,  // (4,4,1)
    const float* __restrict__ ub,    // (4,4)
    float* __restrict__ out)         // (B,256)
{
  constexpr int C = 8;
  constexpr int NCH = 256 / C;     // 32
  constexpr int SLOTS = NCH + 3;
  const int wv   = threadIdx.x >> 6;   // layer
  const int lane = threadIdx.x & 63;
  const int b    = blockIdx.x * 64 + lane;
  float whh[4], wih[4], bsv[4];
#pragma unroll
  for (int gg = 0; gg < 4; ++gg) whh[gg] = rfl(uWhh[wv * 4 + gg]);
  if (wv > 0) {
#pragma unroll
    for (int gg = 0; gg < 4; ++gg) {
      wih[gg] = rfl(uWih[(wv - 1) * 4 + gg]);
      bsv[gg] = rfl(ub[wv * 4 + gg]);
    }
  }
  __shared__ float hring[3][2][C][64];   // layers 0,1,2 feed 1,2,3
  float h = 0.f, cs = 0.f;
  const float4* xp = (const float4*)xw0T;
  for (int s = 0; s < SLOTS; ++s) {
    const int c = s - wv;
    if (c >= 0 && c < NCH) {
      if (wv == 0) {
        float4 xw[C];
#pragma unroll
        for (int u = 0; u < C; ++u) xw[u] = xp[(c * C + u) * 128 + b];  // coalesced
#pragma unroll
        for (int u = 0; u < C; ++u) {
          const float i0 = sigf(fmaf(whh[0], h, xw[u].x));
          const float f0 = sigf(fmaf(whh[1], h, xw[u].y));
          const float g0 = tanhfast(fmaf(whh[2], h, xw[u].z));
          const float o0 = sigf(fmaf(whh[3], h, xw[u].w));
          cs = fmaf(f0, cs, i0 * g0);
          h  = o0 * tanhfast(cs);
          hring[0][c & 1][u][lane] = h;
        }
      } else {
        float hin[C];
#pragma unroll
        for (int u = 0; u < C; ++u) hin[u] = hring[wv - 1][c & 1][u][lane];
#pragma unroll
        for (int u = 0; u < C; ++u) {
          const float pi  = fmaf(whh[0], h, fmaf(wih[0], hin[u], bsv[0]));
          const float pf  = fmaf(whh[1], h, fmaf(wih[1], hin[u], bsv[1]));
          const float pg  = fmaf(whh[2], h, fmaf(wih[2], hin[u], bsv[2]));
          const float po_ = fmaf(whh[3], h, fmaf(wih[3], hin[u], bsv[3]));
          const float il = sigf(pi), fl = sigf(pf), gl = tanhfast(pg), ol = sigf(po_);
          cs = fmaf(fl, cs, il * gl);
          h  = ol * tanhfast(cs);
          if (wv < 3) hring[wv][c & 1][u][lane] = h;
          else        out[(size_t)b * 256 + c * C + u] = h;
        }
      }
    }
    __syncthreads();
  }
}

extern "C" void kernel_launch(void* const* d_in, const int* in_sizes, int n_in,
                              void* d_out, int out_size, void* d_ws, size_t ws_size,
                              hipStream_t stream)
{
  (void)in_sizes; (void)n_in; (void)out_size; (void)ws_size;
  const float* r_c_s = (const float*)d_in[0];
  const float* bWih0 = (const float*)d_in[1];
  const float* bWih  = (const float*)d_in[2];
  const float* bWhh  = (const float*)d_in[3];
  const float* bb    = (const float*)d_in[4];
  const float* uWih0 = (const float*)d_in[5];
  const float* uWih  = (const float*)d_in[6];
  const float* uWhh  = (const float*)d_in[7];
  const float* ub    = (const float*)d_in[8];
  float* outp = (float*)d_out;

  // workspace layout (floats): two (B,T,32) ping-pong, (B,256,32) downsample, (256,B,4) uni-xW
  float* x0  = (float*)d_ws;
  float* x1  = x0  + (size_t)128 * 2048 * 32;
  float* dsb = x1  + (size_t)128 * 2048 * 32;
  float* xw0 = dsb + (size_t)128 * 256 * 32;

  const dim3 grid(256), block(192);
  bilstm_layer<24, false><<<grid, block, 0, stream>>>(r_c_s, bWih0,               bWhh + 0,               bb + 0,          x0);
  bilstm_layer<32, false><<<grid, block, 0, stream>>>(x0,    bWih + 0 * 2*64*32,  bWhh + 1 * 2*64*16,     bb + 1 * 2*64,   x1);
  bilstm_layer<32, false><<<grid, block, 0, stream>>>(x1,    bWih + 1 * 2*64*32,  bWhh + 2 * 2*64*16,     bb + 2 * 2*64,   x0);
  bilstm_layer<32, true ><<<grid, block, 0, stream>>>(x0,    bWih + 2 * 2*64*32,  bWhh + 3 * 2*64*16,     bb + 3 * 2*64,   dsb);
  uni_xw0      <<<dim3(128), dim3(256), 0, stream>>>(dsb, uWih0, ub, xw0);
  uni_stack_pipe<<<dim3(2),  dim3(256), 0, stream>>>(xw0, uWih, uWhh, ub, outp);
}